// Round 9
// baseline (212.951 us; speedup 1.0000x reference)
//
#include <hip/hip_runtime.h>
#include <hip/hip_cooperative_groups.h>
#include <hip/hip_bf16.h>
#include <math.h>

namespace cg = cooperative_groups;

#define NN 1024   // nodes
#define FD 64     // features
#define EE 65536  // edges
#define HD 32     // hidden

typedef __attribute__((ext_vector_type(8))) short short8;
typedef __attribute__((ext_vector_type(4))) float floatx4;

__device__ __forceinline__ float sigmoid_f(float z) {
  return 1.0f / (1.0f + expf(-z));
}
__device__ __forceinline__ float sigmoid_fast(float z) {
  return 1.0f / (1.0f + __expf(-z));
}

__device__ __forceinline__ unsigned pack_bf16_trunc(float hi, float lo) {
  unsigned a = __builtin_bit_cast(unsigned, hi);
  unsigned b = __builtin_bit_cast(unsigned, lo);
  return __builtin_amdgcn_perm(a, b, 0x07060302u);
}

__device__ __forceinline__ short8 pack8(const float* v) {
  union { unsigned u[4]; short8 s; } p;
#pragma unroll
  for (int t = 0; t < 4; ++t) p.u[t] = pack_bf16_trunc(v[2 * t + 1], v[2 * t]);
  return p.s;
}

struct Frag3 { short8 a0, a1, a2; };

// 3-way bf16 split (exact: 8+8+8 mantissa bits) of 8 fp32 values.
__device__ __forceinline__ Frag3 split_pack(const float* v) {
  float r[8], r2[8];
#pragma unroll
  for (int t = 0; t < 8; ++t) {
    const unsigned uv = __builtin_bit_cast(unsigned, v[t]);
    const float f0 = __builtin_bit_cast(float, uv & 0xFFFF0000u);
    const float rr = v[t] - f0;
    const unsigned ur = __builtin_bit_cast(unsigned, rr);
    const float f1 = __builtin_bit_cast(float, ur & 0xFFFF0000u);
    r[t] = rr;
    r2[t] = rr - f1;
  }
  Frag3 f;
  f.a0 = pack8(v);
  f.a1 = pack8(r);
  f.a2 = pack8(r2);
  return f;
}

// ---------------------------------------------------------------------------
// Phase-A helper: pre[which][node][h] for 4 nodes (one 256-thread block).
// ---------------------------------------------------------------------------
__device__ __forceinline__ void build_pre_block(
    int blk, int t, const float* __restrict__ x, const float* __restrict__ W1,
    const float* __restrict__ b1, float* __restrict__ pre) {
  const int node = blk * 4 + (t >> 6);
  const int which = (t >> 5) & 1;
  const int h = t & 31;
  const float* xr = x + node * FD;
  const float* wp = W1 + which * FD * HD + h;
  float a0 = which ? 0.0f : b1[h], a1 = 0.0f, a2 = 0.0f, a3 = 0.0f;
#pragma unroll
  for (int f = 0; f < FD; f += 4) {
    a0 = fmaf(xr[f + 0], wp[(f + 0) * HD], a0);
    a1 = fmaf(xr[f + 1], wp[(f + 1) * HD], a1);
    a2 = fmaf(xr[f + 2], wp[(f + 2) * HD], a2);
    a3 = fmaf(xr[f + 3], wp[(f + 3) * HD], a3);
  }
  pre[which * (NN * HD) + node * HD + h] = (a0 + a1) + (a2 + a3);
}

__device__ __forceinline__ void build_wt_block(
    int t, const float* __restrict__ W1, short* __restrict__ Wt0,
    short* __restrict__ Wt1, short* __restrict__ Wt2) {
  for (int idx = t; idx < 32 * 128; idx += 256) {
    const int h = idx >> 7;
    const int k = idx & 127;
    const int f = k & 63;
    const int b = 2 + (k >> 6);
    const float v = W1[(b * FD + f) * HD + h];
    const unsigned uv = __builtin_bit_cast(unsigned, v);
    const unsigned u0 = uv & 0xFFFF0000u;
    const float f0 = __builtin_bit_cast(float, u0);
    const float r = v - f0;
    const unsigned u1 = __builtin_bit_cast(unsigned, r) & 0xFFFF0000u;
    const float f1 = __builtin_bit_cast(float, u1);
    const float r2 = r - f1;
    const unsigned u2 = __builtin_bit_cast(unsigned, r2) & 0xFFFF0000u;
    Wt0[idx] = (short)(u0 >> 16);
    Wt1[idx] = (short)(u1 >> 16);
    Wt2[idx] = (short)(u2 >> 16);
  }
}

// ---------------------------------------------------------------------------
// Edge helper: 12 split-MFMAs for one 8-feature chunk.
// ---------------------------------------------------------------------------
__device__ __forceinline__ void edge_chunk(
    const float* feat, const short* __restrict__ Wt0,
    const short* __restrict__ Wt1, const short* __restrict__ Wt2,
    int c, int q, int kc, floatx4& acc0, floatx4& acc1) {
  const Frag3 B = split_pack(feat);
  const int off0 = c * 128 + kc * 32 + q * 8;
  const int off1 = (16 + c) * 128 + kc * 32 + q * 8;
  const short8 A00 = *(const short8*)(Wt0 + off0);
  const short8 A01 = *(const short8*)(Wt1 + off0);
  const short8 A02 = *(const short8*)(Wt2 + off0);
  const short8 A10 = *(const short8*)(Wt0 + off1);
  const short8 A11 = *(const short8*)(Wt1 + off1);
  const short8 A12 = *(const short8*)(Wt2 + off1);
  acc0 = __builtin_amdgcn_mfma_f32_16x16x32_bf16(A00, B.a0, acc0, 0, 0, 0);
  acc0 = __builtin_amdgcn_mfma_f32_16x16x32_bf16(A01, B.a0, acc0, 0, 0, 0);
  acc0 = __builtin_amdgcn_mfma_f32_16x16x32_bf16(A02, B.a0, acc0, 0, 0, 0);
  acc0 = __builtin_amdgcn_mfma_f32_16x16x32_bf16(A00, B.a1, acc0, 0, 0, 0);
  acc0 = __builtin_amdgcn_mfma_f32_16x16x32_bf16(A01, B.a1, acc0, 0, 0, 0);
  acc0 = __builtin_amdgcn_mfma_f32_16x16x32_bf16(A00, B.a2, acc0, 0, 0, 0);
  acc1 = __builtin_amdgcn_mfma_f32_16x16x32_bf16(A10, B.a0, acc1, 0, 0, 0);
  acc1 = __builtin_amdgcn_mfma_f32_16x16x32_bf16(A11, B.a0, acc1, 0, 0, 0);
  acc1 = __builtin_amdgcn_mfma_f32_16x16x32_bf16(A12, B.a0, acc1, 0, 0, 0);
  acc1 = __builtin_amdgcn_mfma_f32_16x16x32_bf16(A10, B.a1, acc1, 0, 0, 0);
  acc1 = __builtin_amdgcn_mfma_f32_16x16x32_bf16(A11, B.a1, acc1, 0, 0, 0);
  acc1 = __builtin_amdgcn_mfma_f32_16x16x32_bf16(A10, B.a2, acc1, 0, 0, 0);
}

// ---------------------------------------------------------------------------
// Work-unit bodies (shared by cooperative kernel and the fallback path).
// ---------------------------------------------------------------------------
__device__ __forceinline__ void dense_unit(
    int vb, int w, int lane, float (*mir)[256],
    const float* __restrict__ x, const float* __restrict__ pre,
    const short* __restrict__ Wt0, const float* __restrict__ W2,
    const float* __restrict__ b2, float* __restrict__ outP) {
  const int q = lane >> 4;
  const int c = lane & 15;
  // tile id T in [0, 2080): T = a(a+1)/2 + b, 0 <= b <= a < 64
  const int T = vb * 4 + w;
  int a = (int)((sqrtf(8.0f * (float)T + 1.0f) - 1.0f) * 0.5f);
  while ((a + 1) * (a + 2) / 2 <= T) ++a;
  while (a * (a + 1) / 2 > T) --a;
  const int b = T - a * (a + 1) / 2;
  const int j0 = a * 16;
  const int i0 = b * 16;
  const bool offdiag = (a != b);

  short8 Af[2][4];
#pragma unroll
  for (int n = 0; n < 2; ++n)
#pragma unroll
    for (int s = 0; s < 4; ++s)
      Af[n][s] = *(const short8*)(Wt0 + (n * 16 + c) * 128 + s * 32 + q * 8);

  const float* xj = x + (size_t)(j0 + c) * FD;
  float jA[8], jB[8];
#pragma unroll
  for (int t = 0; t < 4; ++t) {
    jA[t] = xj[q * 8 + t];      jA[4 + t] = xj[q * 8 + 4 + t];
    jB[t] = xj[32 + q * 8 + t]; jB[4 + t] = xj[32 + q * 8 + 4 + t];
  }

  const floatx4 psA_j = *(const floatx4*)(pre + (j0 + c) * HD + q * 4);
  const floatx4 psB_j = *(const floatx4*)(pre + (j0 + c) * HD + 16 + q * 4);
  const floatx4 pdA_j = *(const floatx4*)(pre + NN * HD + (j0 + c) * HD + q * 4);
  const floatx4 pdB_j = *(const floatx4*)(pre + NN * HD + (j0 + c) * HD + 16 + q * 4);
  const floatx4 w2A = *(const floatx4*)(W2 + q * 4);
  const floatx4 w2B = *(const floatx4*)(W2 + 16 + q * 4);
  const float b2v = b2[0];

  for (int ii = 0; ii < 16; ++ii) {
    const int i = i0 + ii;
    const float* xi = x + (size_t)i * FD;
    const floatx4 psA_i = *(const floatx4*)(pre + i * HD + q * 4);
    const floatx4 psB_i = *(const floatx4*)(pre + i * HD + 16 + q * 4);
    floatx4 acc0 = {0.0f, 0.0f, 0.0f, 0.0f};
    floatx4 acc1 = {0.0f, 0.0f, 0.0f, 0.0f};

    {
      const floatx4 i0v = *(const floatx4*)(xi + q * 8);
      const floatx4 i1v = *(const floatx4*)(xi + q * 8 + 4);
      float ad[8], pr[8];
#pragma unroll
      for (int t = 0; t < 4; ++t) {
        ad[t] = fabsf(i0v[t] - jA[t]);         pr[t] = i0v[t] * jA[t];
        ad[4 + t] = fabsf(i1v[t] - jA[4 + t]); pr[4 + t] = i1v[t] * jA[4 + t];
      }
      const short8 fad = pack8(ad);
      const short8 fpr = pack8(pr);
      acc0 = __builtin_amdgcn_mfma_f32_16x16x32_bf16(Af[0][0], fad, acc0, 0, 0, 0);
      acc1 = __builtin_amdgcn_mfma_f32_16x16x32_bf16(Af[1][0], fad, acc1, 0, 0, 0);
      acc0 = __builtin_amdgcn_mfma_f32_16x16x32_bf16(Af[0][2], fpr, acc0, 0, 0, 0);
      acc1 = __builtin_amdgcn_mfma_f32_16x16x32_bf16(Af[1][2], fpr, acc1, 0, 0, 0);
    }
    {
      const floatx4 i0v = *(const floatx4*)(xi + 32 + q * 8);
      const floatx4 i1v = *(const floatx4*)(xi + 32 + q * 8 + 4);
      float ad[8], pr[8];
#pragma unroll
      for (int t = 0; t < 4; ++t) {
        ad[t] = fabsf(i0v[t] - jB[t]);         pr[t] = i0v[t] * jB[t];
        ad[4 + t] = fabsf(i1v[t] - jB[4 + t]); pr[4 + t] = i1v[t] * jB[4 + t];
      }
      const short8 fad = pack8(ad);
      const short8 fpr = pack8(pr);
      acc0 = __builtin_amdgcn_mfma_f32_16x16x32_bf16(Af[0][1], fad, acc0, 0, 0, 0);
      acc1 = __builtin_amdgcn_mfma_f32_16x16x32_bf16(Af[1][1], fad, acc1, 0, 0, 0);
      acc0 = __builtin_amdgcn_mfma_f32_16x16x32_bf16(Af[0][3], fpr, acc0, 0, 0, 0);
      acc1 = __builtin_amdgcn_mfma_f32_16x16x32_bf16(Af[1][3], fpr, acc1, 0, 0, 0);
    }

    float tv = 0.0f;
#pragma unroll
    for (int r = 0; r < 4; ++r) {
      tv = fmaf(fmaxf(acc0[r] + psA_i[r] + pdA_j[r], 0.0f), w2A[r], tv);
      tv = fmaf(fmaxf(acc1[r] + psB_i[r] + pdB_j[r], 0.0f), w2B[r], tv);
    }
    tv += __shfl_xor(tv, 16);
    tv += __shfl_xor(tv, 32);
    if (lane < 16) {
      outP[(size_t)i * NN + j0 + lane] = sigmoid_fast(tv + b2v);
    }

    if (offdiag) {
      const floatx4 pdA_i = *(const floatx4*)(pre + NN * HD + i * HD + q * 4);
      const floatx4 pdB_i = *(const floatx4*)(pre + NN * HD + i * HD + 16 + q * 4);
      float tm = 0.0f;
#pragma unroll
      for (int r = 0; r < 4; ++r) {
        tm = fmaf(fmaxf(acc0[r] + psA_j[r] + pdA_i[r], 0.0f), w2A[r], tm);
        tm = fmaf(fmaxf(acc1[r] + psB_j[r] + pdB_i[r], 0.0f), w2B[r], tm);
      }
      tm += __shfl_xor(tm, 16);
      tm += __shfl_xor(tm, 32);
      if (lane < 16) {
        mir[w][ii * 16 + lane] = sigmoid_fast(tm + b2v);
      }
    }
  }

  if (offdiag) {
    const int r = lane >> 2;
    const int g = lane & 3;
    floatx4 v;
#pragma unroll
    for (int t = 0; t < 4; ++t) v[t] = mir[w][(4 * g + t) * 16 + r];
    *(floatx4*)(outP + (size_t)(j0 + r) * NN + i0 + 4 * g) = v;
  }
}

__device__ __forceinline__ void edge_unit(
    int vb, int w, int lane,
    const float* __restrict__ x, const int* __restrict__ eidx,
    const float* __restrict__ pre, const short* __restrict__ Wt0,
    const short* __restrict__ Wt1, const short* __restrict__ Wt2,
    const float* __restrict__ W2, const float* __restrict__ b2,
    float* __restrict__ out) {
  const int q = lane >> 4;
  const int c = lane & 15;
  const int e0 = (vb * 4 + w) * 16;

  const bool is64 = (eidx[1] == 0) && (eidx[3] == 0) && (eidx[5] == 0);
  int s_c, d_c;
  if (is64) {
    s_c = eidx[2 * (e0 + c)];
    d_c = eidx[2 * (EE + e0 + c)];
  } else {
    s_c = eidx[e0 + c];
    d_c = eidx[EE + e0 + c];
  }
  const float* xs = x + (size_t)s_c * FD;
  const float* xd = x + (size_t)d_c * FD;

  floatx4 acc0, acc1;
  {
    const floatx4 psA = *(const floatx4*)(pre + s_c * HD + q * 4);
    const floatx4 psB = *(const floatx4*)(pre + s_c * HD + 16 + q * 4);
    const floatx4 pdA = *(const floatx4*)(pre + NN * HD + d_c * HD + q * 4);
    const floatx4 pdB = *(const floatx4*)(pre + NN * HD + d_c * HD + 16 + q * 4);
#pragma unroll
    for (int r = 0; r < 4; ++r) {
      acc0[r] = psA[r] + pdA[r];
      acc1[r] = psB[r] + pdB[r];
    }
  }

  {
    const floatx4 s0 = *(const floatx4*)(xs + q * 8);
    const floatx4 s1 = *(const floatx4*)(xs + q * 8 + 4);
    const floatx4 d0 = *(const floatx4*)(xd + q * 8);
    const floatx4 d1 = *(const floatx4*)(xd + q * 8 + 4);
    float ad[8], pr[8];
#pragma unroll
    for (int t = 0; t < 4; ++t) {
      ad[t] = fabsf(s0[t] - d0[t]);     pr[t] = s0[t] * d0[t];
      ad[4 + t] = fabsf(s1[t] - d1[t]); pr[4 + t] = s1[t] * d1[t];
    }
    edge_chunk(ad, Wt0, Wt1, Wt2, c, q, 0, acc0, acc1);
    edge_chunk(pr, Wt0, Wt1, Wt2, c, q, 2, acc0, acc1);
  }
  {
    const floatx4 s0 = *(const floatx4*)(xs + 32 + q * 8);
    const floatx4 s1 = *(const floatx4*)(xs + 32 + q * 8 + 4);
    const floatx4 d0 = *(const floatx4*)(xd + 32 + q * 8);
    const floatx4 d1 = *(const floatx4*)(xd + 32 + q * 8 + 4);
    float ad[8], pr[8];
#pragma unroll
    for (int t = 0; t < 4; ++t) {
      ad[t] = fabsf(s0[t] - d0[t]);     pr[t] = s0[t] * d0[t];
      ad[4 + t] = fabsf(s1[t] - d1[t]); pr[4 + t] = s1[t] * d1[t];
    }
    edge_chunk(ad, Wt0, Wt1, Wt2, c, q, 1, acc0, acc1);
    edge_chunk(pr, Wt0, Wt1, Wt2, c, q, 3, acc0, acc1);
  }

  const floatx4 w2A = *(const floatx4*)(W2 + q * 4);
  const floatx4 w2B = *(const floatx4*)(W2 + 16 + q * 4);
  float tv = 0.0f;
#pragma unroll
  for (int r = 0; r < 4; ++r) {
    tv = fmaf(fmaxf(acc0[r], 0.0f), w2A[r], tv);
    tv = fmaf(fmaxf(acc1[r], 0.0f), w2B[r], tv);
  }
  tv += __shfl_xor(tv, 16);
  tv += __shfl_xor(tv, 32);
  if (lane < 16) {
    const int e = e0 + lane;
    const float z = tv + b2[0];
    out[e] = sigmoid_f(z);
    out[EE + e] = (z > -0.40546510810816444f) ? 1.0f : 0.0f;
  }
}

// ---------------------------------------------------------------------------
// Single cooperative dispatch: phase A builds pre+Wt, grid sync, phase B
// runs 1544 virtual blocks (520 dense + 1024 edge) via 768-stride loop.
// ---------------------------------------------------------------------------
#define DENSE_BLOCKS 520
#define COOP_GRID 768

__global__ __launch_bounds__(256, 3) void mega_kernel(
    const float* __restrict__ x, const int* __restrict__ eidx,
    const float* __restrict__ W1, const float* __restrict__ b1,
    float* __restrict__ pre, short* __restrict__ Wt0,
    short* __restrict__ Wt1, short* __restrict__ Wt2,
    const float* __restrict__ W2, const float* __restrict__ b2,
    float* __restrict__ out, float* __restrict__ outP) {
  __shared__ float mir[4][256];
  const int lane = threadIdx.x & 63;
  const int w = threadIdx.x >> 6;

  // ---- phase A: build pre (blocks 0..255) and Wt splits (block 256) ----
  if (blockIdx.x < 256) {
    build_pre_block(blockIdx.x, threadIdx.x, x, W1, b1, pre);
  } else if (blockIdx.x == 256) {
    build_wt_block(threadIdx.x, W1, Wt0, Wt1, Wt2);
  }
  __threadfence();
  cg::this_grid().sync();

  // ---- phase B: 1544 virtual blocks over 768 physical ----
  for (int vb = blockIdx.x; vb < DENSE_BLOCKS + 1024; vb += COOP_GRID) {
    if (vb < DENSE_BLOCKS) {
      dense_unit(vb, w, lane, mir, x, pre, Wt0, W2, b2, outP);
    } else {
      edge_unit(vb - DENSE_BLOCKS, w, lane, x, eidx, pre, Wt0, Wt1, Wt2,
                W2, b2, out);
    }
  }
}

// ---------------------------------------------------------------------------
// Fallback: R8's two-dispatch path (pre kernel + fused kernel).
// ---------------------------------------------------------------------------
__global__ __launch_bounds__(256) void pre_kernel3(
    const float* __restrict__ x, const float* __restrict__ W1,
    const float* __restrict__ b1, float* __restrict__ pre,
    short* __restrict__ Wt0, short* __restrict__ Wt1, short* __restrict__ Wt2) {
  if (blockIdx.x < 256) {
    build_pre_block(blockIdx.x, threadIdx.x, x, W1, b1, pre);
  } else {
    build_wt_block(threadIdx.x, W1, Wt0, Wt1, Wt2);
  }
}

__global__ __launch_bounds__(256, 3) void fused_mfma_kernel(
    const float* __restrict__ x, const int* __restrict__ eidx,
    const float* __restrict__ pre, const short* __restrict__ Wt0,
    const short* __restrict__ Wt1, const short* __restrict__ Wt2,
    const float* __restrict__ W2, const float* __restrict__ b2,
    float* __restrict__ out, float* __restrict__ outP) {
  __shared__ float mir[4][256];
  const int lane = threadIdx.x & 63;
  const int w = threadIdx.x >> 6;
  if (blockIdx.x < DENSE_BLOCKS) {
    dense_unit(blockIdx.x, w, lane, mir, x, pre, Wt0, W2, b2, outP);
  } else {
    edge_unit(blockIdx.x - DENSE_BLOCKS, w, lane, x, eidx, pre, Wt0, Wt1, Wt2,
              W2, b2, out);
  }
}

extern "C" void kernel_launch(void* const* d_in, const int* in_sizes, int n_in,
                              void* d_out, int out_size, void* d_ws, size_t ws_size,
                              hipStream_t stream) {
  const float* x  = (const float*)d_in[0];
  const int*  ei  = (const int*)d_in[1];
  const float* W1 = (const float*)d_in[3];
  const float* b1 = (const float*)d_in[4];
  const float* W2 = (const float*)d_in[5];
  const float* b2 = (const float*)d_in[6];
  float* out  = (float*)d_out;   // [0,EE) probs, [EE,2EE) actions
  float* outP = out + 2 * EE;    // [2EE, 2EE+NN*NN) P

  const size_t pre_bytes = (size_t)2 * NN * HD * sizeof(float);
  const size_t wt_elems = 32 * 128;
  float* pre = (float*)d_ws;
  short* Wt0 = (short*)((char*)d_ws + pre_bytes);
  short* Wt1 = Wt0 + wt_elems;
  short* Wt2 = Wt1 + wt_elems;

  void* args[] = {
    (void*)&x, (void*)&ei, (void*)&W1, (void*)&b1,
    (void*)&pre, (void*)&Wt0, (void*)&Wt1, (void*)&Wt2,
    (void*)&W2, (void*)&b2, (void*)&out, (void*)&outP
  };
  hipError_t err = hipLaunchCooperativeKernel(
      (const void*)mega_kernel, dim3(COOP_GRID), dim3(256), args, 0, stream);
  if (err != hipSuccess) {
    // fallback: proven two-dispatch R8 path
    pre_kernel3<<<257, 256, 0, stream>>>(x, W1, b1, pre, Wt0, Wt1, Wt2);
    fused_mfma_kernel<<<DENSE_BLOCKS + 1024, 256, 0, stream>>>(
        x, ei, pre, Wt0, Wt1, Wt2, W2, b2, out, outP);
  }
}

// Round 10
// 105.745 us; speedup vs baseline: 2.0138x; 2.0138x over previous
//
#include <hip/hip_runtime.h>
#include <hip/hip_bf16.h>
#include <math.h>

#define NN 1024   // nodes
#define FD 64     // features
#define EE 65536  // edges
#define HD 32     // hidden

typedef __attribute__((ext_vector_type(8))) short short8;
typedef __attribute__((ext_vector_type(4))) float floatx4;

__device__ __forceinline__ float sigmoid_f(float z) {
  return 1.0f / (1.0f + expf(-z));
}
__device__ __forceinline__ float sigmoid_fast(float z) {
  return 1.0f / (1.0f + __expf(-z));
}

__device__ __forceinline__ unsigned pack_bf16_trunc(float hi, float lo) {
  unsigned a = __builtin_bit_cast(unsigned, hi);
  unsigned b = __builtin_bit_cast(unsigned, lo);
  return __builtin_amdgcn_perm(a, b, 0x07060302u);
}

__device__ __forceinline__ short8 pack8(const float* v) {
  union { unsigned u[4]; short8 s; } p;
#pragma unroll
  for (int t = 0; t < 4; ++t) p.u[t] = pack_bf16_trunc(v[2 * t + 1], v[2 * t]);
  return p.s;
}

struct Frag3 { short8 a0, a1, a2; };

// 3-way bf16 split (exact: 8+8+8 mantissa bits) of 8 fp32 values.
__device__ __forceinline__ Frag3 split_pack(const float* v) {
  float r[8], r2[8];
#pragma unroll
  for (int t = 0; t < 8; ++t) {
    const unsigned uv = __builtin_bit_cast(unsigned, v[t]);
    const float f0 = __builtin_bit_cast(float, uv & 0xFFFF0000u);
    const float rr = v[t] - f0;
    const unsigned ur = __builtin_bit_cast(unsigned, rr);
    const float f1 = __builtin_bit_cast(float, ur & 0xFFFF0000u);
    r[t] = rr;
    r2[t] = rr - f1;
  }
  Frag3 f;
  f.a0 = pack8(v);
  f.a1 = pack8(r);
  f.a2 = pack8(r2);
  return f;
}

// ---------------------------------------------------------------------------
// Pre-pass (R8): pre[which][node][h]; block 256 builds Wt0/1/2 splits.
// ---------------------------------------------------------------------------
__global__ __launch_bounds__(256) void pre_kernel3(
    const float* __restrict__ x, const float* __restrict__ W1,
    const float* __restrict__ b1, float* __restrict__ pre,
    short* __restrict__ Wt0, short* __restrict__ Wt1, short* __restrict__ Wt2) {
  const int blk = blockIdx.x;
  const int t = threadIdx.x;
  if (blk < 256) {
    const int node = blk * 4 + (t >> 6);
    const int which = (t >> 5) & 1;
    const int h = t & 31;
    const float* xr = x + node * FD;
    const float* wp = W1 + which * FD * HD + h;
    float a0 = which ? 0.0f : b1[h], a1 = 0.0f, a2 = 0.0f, a3 = 0.0f;
#pragma unroll
    for (int f = 0; f < FD; f += 4) {
      a0 = fmaf(xr[f + 0], wp[(f + 0) * HD], a0);
      a1 = fmaf(xr[f + 1], wp[(f + 1) * HD], a1);
      a2 = fmaf(xr[f + 2], wp[(f + 2) * HD], a2);
      a3 = fmaf(xr[f + 3], wp[(f + 3) * HD], a3);
    }
    pre[which * (NN * HD) + node * HD + h] = (a0 + a1) + (a2 + a3);
  } else {
    for (int idx = t; idx < 32 * 128; idx += 256) {
      const int h = idx >> 7;
      const int k = idx & 127;
      const int f = k & 63;
      const int b = 2 + (k >> 6);
      const float v = W1[(b * FD + f) * HD + h];
      const unsigned uv = __builtin_bit_cast(unsigned, v);
      const unsigned u0 = uv & 0xFFFF0000u;
      const float f0 = __builtin_bit_cast(float, u0);
      const float r = v - f0;
      const unsigned u1 = __builtin_bit_cast(unsigned, r) & 0xFFFF0000u;
      const float f1 = __builtin_bit_cast(float, u1);
      const float r2 = r - f1;
      const unsigned u2 = __builtin_bit_cast(unsigned, r2) & 0xFFFF0000u;
      Wt0[idx] = (short)(u0 >> 16);
      Wt1[idx] = (short)(u1 >> 16);
      Wt2[idx] = (short)(u2 >> 16);
    }
  }
}

// ---------------------------------------------------------------------------
// Edge helper: 12 split-MFMAs for one 8-feature chunk.
// ---------------------------------------------------------------------------
__device__ __forceinline__ void edge_chunk(
    const float* feat, const short* __restrict__ Wt0,
    const short* __restrict__ Wt1, const short* __restrict__ Wt2,
    int c, int q, int kc, floatx4& acc0, floatx4& acc1) {
  const Frag3 B = split_pack(feat);
  const int off0 = c * 128 + kc * 32 + q * 8;
  const int off1 = (16 + c) * 128 + kc * 32 + q * 8;
  const short8 A00 = *(const short8*)(Wt0 + off0);
  const short8 A01 = *(const short8*)(Wt1 + off0);
  const short8 A02 = *(const short8*)(Wt2 + off0);
  const short8 A10 = *(const short8*)(Wt0 + off1);
  const short8 A11 = *(const short8*)(Wt1 + off1);
  const short8 A12 = *(const short8*)(Wt2 + off1);
  acc0 = __builtin_amdgcn_mfma_f32_16x16x32_bf16(A00, B.a0, acc0, 0, 0, 0);
  acc0 = __builtin_amdgcn_mfma_f32_16x16x32_bf16(A01, B.a0, acc0, 0, 0, 0);
  acc0 = __builtin_amdgcn_mfma_f32_16x16x32_bf16(A02, B.a0, acc0, 0, 0, 0);
  acc0 = __builtin_amdgcn_mfma_f32_16x16x32_bf16(A00, B.a1, acc0, 0, 0, 0);
  acc0 = __builtin_amdgcn_mfma_f32_16x16x32_bf16(A01, B.a1, acc0, 0, 0, 0);
  acc0 = __builtin_amdgcn_mfma_f32_16x16x32_bf16(A00, B.a2, acc0, 0, 0, 0);
  acc1 = __builtin_amdgcn_mfma_f32_16x16x32_bf16(A10, B.a0, acc1, 0, 0, 0);
  acc1 = __builtin_amdgcn_mfma_f32_16x16x32_bf16(A11, B.a0, acc1, 0, 0, 0);
  acc1 = __builtin_amdgcn_mfma_f32_16x16x32_bf16(A12, B.a0, acc1, 0, 0, 0);
  acc1 = __builtin_amdgcn_mfma_f32_16x16x32_bf16(A10, B.a1, acc1, 0, 0, 0);
  acc1 = __builtin_amdgcn_mfma_f32_16x16x32_bf16(A11, B.a1, acc1, 0, 0, 0);
  acc1 = __builtin_amdgcn_mfma_f32_16x16x32_bf16(A10, B.a2, acc1, 0, 0, 0);
}

// ---------------------------------------------------------------------------
// Fused edge+dense kernel (R8 structure). Dense i-loop register
// double-buffered: iteration i+1's xi/ps loads issue before iteration i's
// compute consumes its values -> vmem latency overlaps VALU+MFMA.
// ---------------------------------------------------------------------------
#define DENSE_BLOCKS 520

__global__ __launch_bounds__(256, 3) void fused_mfma_kernel(
    const float* __restrict__ x, const int* __restrict__ eidx,
    const float* __restrict__ pre, const short* __restrict__ Wt0,
    const short* __restrict__ Wt1, const short* __restrict__ Wt2,
    const float* __restrict__ W2, const float* __restrict__ b2,
    float* __restrict__ out, float* __restrict__ outP) {
  __shared__ float mir[4][256];
  const int lane = threadIdx.x & 63;
  const int w = threadIdx.x >> 6;
  const int q = lane >> 4;
  const int c = lane & 15;

  if (blockIdx.x < DENSE_BLOCKS) {
    // ---------------- dense path: symmetric bilinear, triangular tiling ----
    const int T = blockIdx.x * 4 + w;
    int a = (int)((sqrtf(8.0f * (float)T + 1.0f) - 1.0f) * 0.5f);
    while ((a + 1) * (a + 2) / 2 <= T) ++a;
    while (a * (a + 1) / 2 > T) --a;
    const int b = T - a * (a + 1) / 2;
    const int j0 = a * 16;
    const int i0 = b * 16;
    const bool offdiag = (a != b);

    short8 Af[2][4];
#pragma unroll
    for (int n = 0; n < 2; ++n)
#pragma unroll
      for (int s = 0; s < 4; ++s)
        Af[n][s] = *(const short8*)(Wt0 + (n * 16 + c) * 128 + s * 32 + q * 8);

    const float* xj = x + (size_t)(j0 + c) * FD;
    float jA[8], jB[8];
#pragma unroll
    for (int t = 0; t < 4; ++t) {
      jA[t] = xj[q * 8 + t];      jA[4 + t] = xj[q * 8 + 4 + t];
      jB[t] = xj[32 + q * 8 + t]; jB[4 + t] = xj[32 + q * 8 + 4 + t];
    }

    const floatx4 psA_j = *(const floatx4*)(pre + (j0 + c) * HD + q * 4);
    const floatx4 psB_j = *(const floatx4*)(pre + (j0 + c) * HD + 16 + q * 4);
    const floatx4 pdA_j = *(const floatx4*)(pre + NN * HD + (j0 + c) * HD + q * 4);
    const floatx4 pdB_j = *(const floatx4*)(pre + NN * HD + (j0 + c) * HD + 16 + q * 4);
    const floatx4 w2A = *(const floatx4*)(W2 + q * 4);
    const floatx4 w2B = *(const floatx4*)(W2 + 16 + q * 4);
    const float b2v = b2[0];

    // prefetch iteration 0
    const float* xi0 = x + (size_t)i0 * FD;
    floatx4 nA0 = *(const floatx4*)(xi0 + q * 8);
    floatx4 nA1 = *(const floatx4*)(xi0 + q * 8 + 4);
    floatx4 nB0 = *(const floatx4*)(xi0 + 32 + q * 8);
    floatx4 nB1 = *(const floatx4*)(xi0 + 32 + q * 8 + 4);
    floatx4 nPA = *(const floatx4*)(pre + i0 * HD + q * 4);
    floatx4 nPB = *(const floatx4*)(pre + i0 * HD + 16 + q * 4);

    for (int ii = 0; ii < 16; ++ii) {
      const int i = i0 + ii;
      // consume current, immediately issue next iteration's loads
      const floatx4 iA0 = nA0, iA1 = nA1, iB0 = nB0, iB1 = nB1;
      const floatx4 psA_i = nPA, psB_i = nPB;
      if (ii < 15) {
        const float* xin = x + (size_t)(i + 1) * FD;
        nA0 = *(const floatx4*)(xin + q * 8);
        nA1 = *(const floatx4*)(xin + q * 8 + 4);
        nB0 = *(const floatx4*)(xin + 32 + q * 8);
        nB1 = *(const floatx4*)(xin + 32 + q * 8 + 4);
        nPA = *(const floatx4*)(pre + (i + 1) * HD + q * 4);
        nPB = *(const floatx4*)(pre + (i + 1) * HD + 16 + q * 4);
      }

      floatx4 acc0 = {0.0f, 0.0f, 0.0f, 0.0f};
      floatx4 acc1 = {0.0f, 0.0f, 0.0f, 0.0f};
      {
        float ad[8], pr[8];
#pragma unroll
        for (int t = 0; t < 4; ++t) {
          ad[t] = fabsf(iA0[t] - jA[t]);         pr[t] = iA0[t] * jA[t];
          ad[4 + t] = fabsf(iA1[t] - jA[4 + t]); pr[4 + t] = iA1[t] * jA[4 + t];
        }
        const short8 fad = pack8(ad);
        const short8 fpr = pack8(pr);
        acc0 = __builtin_amdgcn_mfma_f32_16x16x32_bf16(Af[0][0], fad, acc0, 0, 0, 0);
        acc1 = __builtin_amdgcn_mfma_f32_16x16x32_bf16(Af[1][0], fad, acc1, 0, 0, 0);
        acc0 = __builtin_amdgcn_mfma_f32_16x16x32_bf16(Af[0][2], fpr, acc0, 0, 0, 0);
        acc1 = __builtin_amdgcn_mfma_f32_16x16x32_bf16(Af[1][2], fpr, acc1, 0, 0, 0);
      }
      {
        float ad[8], pr[8];
#pragma unroll
        for (int t = 0; t < 4; ++t) {
          ad[t] = fabsf(iB0[t] - jB[t]);         pr[t] = iB0[t] * jB[t];
          ad[4 + t] = fabsf(iB1[t] - jB[4 + t]); pr[4 + t] = iB1[t] * jB[4 + t];
        }
        const short8 fad = pack8(ad);
        const short8 fpr = pack8(pr);
        acc0 = __builtin_amdgcn_mfma_f32_16x16x32_bf16(Af[0][1], fad, acc0, 0, 0, 0);
        acc1 = __builtin_amdgcn_mfma_f32_16x16x32_bf16(Af[1][1], fad, acc1, 0, 0, 0);
        acc0 = __builtin_amdgcn_mfma_f32_16x16x32_bf16(Af[0][3], fpr, acc0, 0, 0, 0);
        acc1 = __builtin_amdgcn_mfma_f32_16x16x32_bf16(Af[1][3], fpr, acc1, 0, 0, 0);
      }

      // forward: P[i][j0+c]
      float tv = 0.0f;
#pragma unroll
      for (int r = 0; r < 4; ++r) {
        tv = fmaf(fmaxf(acc0[r] + psA_i[r] + pdA_j[r], 0.0f), w2A[r], tv);
        tv = fmaf(fmaxf(acc1[r] + psB_i[r] + pdB_j[r], 0.0f), w2B[r], tv);
      }
      tv += __shfl_xor(tv, 16);
      tv += __shfl_xor(tv, 32);
      if (lane < 16) {
        outP[(size_t)i * NN + j0 + lane] = sigmoid_fast(tv + b2v);
      }

      if (offdiag) {
        const floatx4 pdA_i = *(const floatx4*)(pre + NN * HD + i * HD + q * 4);
        const floatx4 pdB_i = *(const floatx4*)(pre + NN * HD + i * HD + 16 + q * 4);
        float tm = 0.0f;
#pragma unroll
        for (int r = 0; r < 4; ++r) {
          tm = fmaf(fmaxf(acc0[r] + psA_j[r] + pdA_i[r], 0.0f), w2A[r], tm);
          tm = fmaf(fmaxf(acc1[r] + psB_j[r] + pdB_i[r], 0.0f), w2B[r], tm);
        }
        tm += __shfl_xor(tm, 16);
        tm += __shfl_xor(tm, 32);
        if (lane < 16) {
          mir[w][ii * 16 + lane] = sigmoid_fast(tm + b2v);
        }
      }
    }

    if (offdiag) {
      // coalesced mirror store: 16 rows x 64B contiguous segments
      const int r = lane >> 2;
      const int g = lane & 3;
      floatx4 v;
#pragma unroll
      for (int t = 0; t < 4; ++t) v[t] = mir[w][(4 * g + t) * 16 + r];
      *(floatx4*)(outP + (size_t)(j0 + r) * NN + i0 + 4 * g) = v;
    }
  } else {
    // ---------------- edge path: split-MFMA, fp32-accurate ----------------
    const int e0 = ((blockIdx.x - DENSE_BLOCKS) * 4 + w) * 16;

    const bool is64 = (eidx[1] == 0) && (eidx[3] == 0) && (eidx[5] == 0);
    int s_c, d_c;
    if (is64) {
      s_c = eidx[2 * (e0 + c)];
      d_c = eidx[2 * (EE + e0 + c)];
    } else {
      s_c = eidx[e0 + c];
      d_c = eidx[EE + e0 + c];
    }
    const float* xs = x + (size_t)s_c * FD;
    const float* xd = x + (size_t)d_c * FD;

    floatx4 acc0, acc1;
    {
      const floatx4 psA = *(const floatx4*)(pre + s_c * HD + q * 4);
      const floatx4 psB = *(const floatx4*)(pre + s_c * HD + 16 + q * 4);
      const floatx4 pdA = *(const floatx4*)(pre + NN * HD + d_c * HD + q * 4);
      const floatx4 pdB = *(const floatx4*)(pre + NN * HD + d_c * HD + 16 + q * 4);
#pragma unroll
      for (int r = 0; r < 4; ++r) {
        acc0[r] = psA[r] + pdA[r];
        acc1[r] = psB[r] + pdB[r];
      }
    }

    {
      const floatx4 s0 = *(const floatx4*)(xs + q * 8);
      const floatx4 s1 = *(const floatx4*)(xs + q * 8 + 4);
      const floatx4 d0 = *(const floatx4*)(xd + q * 8);
      const floatx4 d1 = *(const floatx4*)(xd + q * 8 + 4);
      float ad[8], pr[8];
#pragma unroll
      for (int t = 0; t < 4; ++t) {
        ad[t] = fabsf(s0[t] - d0[t]);     pr[t] = s0[t] * d0[t];
        ad[4 + t] = fabsf(s1[t] - d1[t]); pr[4 + t] = s1[t] * d1[t];
      }
      edge_chunk(ad, Wt0, Wt1, Wt2, c, q, 0, acc0, acc1);
      edge_chunk(pr, Wt0, Wt1, Wt2, c, q, 2, acc0, acc1);
    }
    {
      const floatx4 s0 = *(const floatx4*)(xs + 32 + q * 8);
      const floatx4 s1 = *(const floatx4*)(xs + 32 + q * 8 + 4);
      const floatx4 d0 = *(const floatx4*)(xd + 32 + q * 8);
      const floatx4 d1 = *(const floatx4*)(xd + 32 + q * 8 + 4);
      float ad[8], pr[8];
#pragma unroll
      for (int t = 0; t < 4; ++t) {
        ad[t] = fabsf(s0[t] - d0[t]);     pr[t] = s0[t] * d0[t];
        ad[4 + t] = fabsf(s1[t] - d1[t]); pr[4 + t] = s1[t] * d1[t];
      }
      edge_chunk(ad, Wt0, Wt1, Wt2, c, q, 1, acc0, acc1);
      edge_chunk(pr, Wt0, Wt1, Wt2, c, q, 3, acc0, acc1);
    }

    const floatx4 w2A = *(const floatx4*)(W2 + q * 4);
    const floatx4 w2B = *(const floatx4*)(W2 + 16 + q * 4);
    float tv = 0.0f;
#pragma unroll
    for (int r = 0; r < 4; ++r) {
      tv = fmaf(fmaxf(acc0[r], 0.0f), w2A[r], tv);
      tv = fmaf(fmaxf(acc1[r], 0.0f), w2B[r], tv);
    }
    tv += __shfl_xor(tv, 16);
    tv += __shfl_xor(tv, 32);
    if (lane < 16) {
      const int e = e0 + lane;
      const float z = tv + b2[0];
      out[e] = sigmoid_f(z);
      out[EE + e] = (z > -0.40546510810816444f) ? 1.0f : 0.0f;
    }
  }
}

// ---------------------------------------------------------------------------
// Fallbacks (no-workspace path)
// ---------------------------------------------------------------------------
__device__ __forceinline__ float pair_logit_full(
    const float* __restrict__ xs, const float* __restrict__ xd,
    const float* __restrict__ W1, const float* __restrict__ b1,
    const float* __restrict__ W2, const float b2v) {
  float acc[HD];
#pragma unroll
  for (int h = 0; h < HD; ++h) acc[h] = b1[h];
#pragma unroll 1
  for (int f = 0; f < FD; ++f) {
    const float a = xs[f], b = xd[f];
    const float ad = fabsf(a - b), pr = a * b;
#pragma unroll
    for (int h = 0; h < HD; ++h) {
      float t0 = fmaf(a, W1[f * HD + h], acc[h]);
      t0 = fmaf(b, W1[(FD + f) * HD + h], t0);
      t0 = fmaf(ad, W1[(2 * FD + f) * HD + h], t0);
      acc[h] = fmaf(pr, W1[(3 * FD + f) * HD + h], t0);
    }
  }
  float z = b2v;
#pragma unroll
  for (int h = 0; h < HD; ++h) z = fmaf(fmaxf(acc[h], 0.0f), W2[h], z);
  return z;
}

__global__ __launch_bounds__(256) void edge_kernel_fb(
    const float* __restrict__ x, const int* __restrict__ eidx,
    const float* __restrict__ W1, const float* __restrict__ b1,
    const float* __restrict__ W2, const float* __restrict__ b2,
    float* __restrict__ out) {
  const int e = blockIdx.x * 256 + threadIdx.x;
  const bool is64 = (eidx[1] == 0) && (eidx[3] == 0) && (eidx[5] == 0);
  int s, d;
  if (is64) { s = eidx[2 * e]; d = eidx[2 * (EE + e)]; }
  else { s = eidx[e]; d = eidx[EE + e]; }
  const float z = pair_logit_full(x + (size_t)s * FD, x + (size_t)d * FD,
                                  W1, b1, W2, b2[0]);
  const float p = sigmoid_f(z);
  out[e] = p;
  out[EE + e] = (p > 0.4f) ? 1.0f : 0.0f;
}

__global__ __launch_bounds__(256) void dense_full_fb(
    const float* __restrict__ x, const float* __restrict__ W1,
    const float* __restrict__ b1, const float* __restrict__ W2,
    const float* __restrict__ b2, float* __restrict__ outP) {
  const int j = blockIdx.x * 64 + threadIdx.x % 64;
  const int i = blockIdx.y * 4 + threadIdx.x / 64;
  const float z = pair_logit_full(x + (size_t)i * FD, x + (size_t)j * FD,
                                  W1, b1, W2, b2[0]);
  outP[(size_t)i * NN + j] = sigmoid_f(z);
}

extern "C" void kernel_launch(void* const* d_in, const int* in_sizes, int n_in,
                              void* d_out, int out_size, void* d_ws, size_t ws_size,
                              hipStream_t stream) {
  const float* x  = (const float*)d_in[0];
  const int*  ei  = (const int*)d_in[1];
  const float* W1 = (const float*)d_in[3];
  const float* b1 = (const float*)d_in[4];
  const float* W2 = (const float*)d_in[5];
  const float* b2 = (const float*)d_in[6];
  float* out  = (float*)d_out;   // [0,EE) probs, [EE,2EE) actions
  float* outP = out + 2 * EE;    // [2EE, 2EE+NN*NN) P

  const size_t pre_bytes = (size_t)2 * NN * HD * sizeof(float);
  const size_t wt_elems = 32 * 128;
  const size_t need = pre_bytes + 3 * wt_elems * sizeof(short);
  if (ws_size >= need) {
    float* pre = (float*)d_ws;
    short* Wt0 = (short*)((char*)d_ws + pre_bytes);
    short* Wt1 = Wt0 + wt_elems;
    short* Wt2 = Wt1 + wt_elems;
    pre_kernel3<<<257, 256, 0, stream>>>(x, W1, b1, pre, Wt0, Wt1, Wt2);
    fused_mfma_kernel<<<DENSE_BLOCKS + 1024, 256, 0, stream>>>(
        x, ei, pre, Wt0, Wt1, Wt2, W2, b2, out, outP);
  } else {
    edge_kernel_fb<<<EE / 256, 256, 0, stream>>>(x, ei, W1, b1, W2, b2, out);
    dense_full_fb<<<dim3(NN / 64, NN / 4), 256, 0, stream>>>(
        x, W1, b1, W2, b2, outP);
  }
}

// Round 11
// 94.046 us; speedup vs baseline: 2.2643x; 1.1244x over previous
//
#include <hip/hip_runtime.h>
#include <hip/hip_bf16.h>
#include <math.h>

#define NN 1024   // nodes
#define FD 64     // features
#define EE 65536  // edges
#define HD 32     // hidden
#define WSTRIDE 136  // LDS row stride in shorts (128 + 8 pad: 2-way banks, 16B-aligned)

typedef __attribute__((ext_vector_type(8))) short short8;
typedef __attribute__((ext_vector_type(4))) float floatx4;

__device__ __forceinline__ float sigmoid_f(float z) {
  return 1.0f / (1.0f + expf(-z));
}
__device__ __forceinline__ float sigmoid_fast(float z) {
  return 1.0f / (1.0f + __expf(-z));
}

__device__ __forceinline__ unsigned pack_bf16_trunc(float hi, float lo) {
  unsigned a = __builtin_bit_cast(unsigned, hi);
  unsigned b = __builtin_bit_cast(unsigned, lo);
  return __builtin_amdgcn_perm(a, b, 0x07060302u);
}

__device__ __forceinline__ short8 pack8(const float* v) {
  union { unsigned u[4]; short8 s; } p;
#pragma unroll
  for (int t = 0; t < 4; ++t) p.u[t] = pack_bf16_trunc(v[2 * t + 1], v[2 * t]);
  return p.s;
}

struct Frag3 { short8 a0, a1, a2; };

// 3-way bf16 split (exact: 8+8+8 mantissa bits) of 8 fp32 values.
__device__ __forceinline__ Frag3 split_pack(const float* v) {
  float r[8], r2[8];
#pragma unroll
  for (int t = 0; t < 8; ++t) {
    const unsigned uv = __builtin_bit_cast(unsigned, v[t]);
    const float f0 = __builtin_bit_cast(float, uv & 0xFFFF0000u);
    const float rr = v[t] - f0;
    const unsigned ur = __builtin_bit_cast(unsigned, rr);
    const float f1 = __builtin_bit_cast(float, ur & 0xFFFF0000u);
    r[t] = rr;
    r2[t] = rr - f1;
  }
  Frag3 f;
  f.a0 = pack8(v);
  f.a1 = pack8(r);
  f.a2 = pack8(r2);
  return f;
}

// ---------------------------------------------------------------------------
// Pre-pass: pre[which][node][h]; block 256 builds Wt0/1/2 splits.
// ---------------------------------------------------------------------------
__global__ __launch_bounds__(256) void pre_kernel3(
    const float* __restrict__ x, const float* __restrict__ W1,
    const float* __restrict__ b1, float* __restrict__ pre,
    short* __restrict__ Wt0, short* __restrict__ Wt1, short* __restrict__ Wt2) {
  const int blk = blockIdx.x;
  const int t = threadIdx.x;
  if (blk < 256) {
    const int node = blk * 4 + (t >> 6);
    const int which = (t >> 5) & 1;
    const int h = t & 31;
    const float* xr = x + node * FD;
    const float* wp = W1 + which * FD * HD + h;
    float a0 = which ? 0.0f : b1[h], a1 = 0.0f, a2 = 0.0f, a3 = 0.0f;
#pragma unroll
    for (int f = 0; f < FD; f += 4) {
      a0 = fmaf(xr[f + 0], wp[(f + 0) * HD], a0);
      a1 = fmaf(xr[f + 1], wp[(f + 1) * HD], a1);
      a2 = fmaf(xr[f + 2], wp[(f + 2) * HD], a2);
      a3 = fmaf(xr[f + 3], wp[(f + 3) * HD], a3);
    }
    pre[which * (NN * HD) + node * HD + h] = (a0 + a1) + (a2 + a3);
  } else {
    for (int idx = t; idx < 32 * 128; idx += 256) {
      const int h = idx >> 7;
      const int k = idx & 127;
      const int f = k & 63;
      const int b = 2 + (k >> 6);
      const float v = W1[(b * FD + f) * HD + h];
      const unsigned uv = __builtin_bit_cast(unsigned, v);
      const unsigned u0 = uv & 0xFFFF0000u;
      const float f0 = __builtin_bit_cast(float, u0);
      const float r = v - f0;
      const unsigned u1 = __builtin_bit_cast(unsigned, r) & 0xFFFF0000u;
      const float f1 = __builtin_bit_cast(float, u1);
      const float r2 = r - f1;
      const unsigned u2 = __builtin_bit_cast(unsigned, r2) & 0xFFFF0000u;
      Wt0[idx] = (short)(u0 >> 16);
      Wt1[idx] = (short)(u1 >> 16);
      Wt2[idx] = (short)(u2 >> 16);
    }
  }
}

// ---------------------------------------------------------------------------
// Edge helper: 12 split-MFMAs for one 8-feature chunk. A-frags from LDS.
// ---------------------------------------------------------------------------
__device__ __forceinline__ void edge_chunk(
    const float* feat, const short* sWt0, const short* sWt1, const short* sWt2,
    int c, int q, int kc, floatx4& acc0, floatx4& acc1) {
  const Frag3 B = split_pack(feat);
  const int off0 = c * WSTRIDE + kc * 32 + q * 8;
  const int off1 = (16 + c) * WSTRIDE + kc * 32 + q * 8;
  const short8 A00 = *(const short8*)(sWt0 + off0);
  const short8 A01 = *(const short8*)(sWt1 + off0);
  const short8 A02 = *(const short8*)(sWt2 + off0);
  const short8 A10 = *(const short8*)(sWt0 + off1);
  const short8 A11 = *(const short8*)(sWt1 + off1);
  const short8 A12 = *(const short8*)(sWt2 + off1);
  acc0 = __builtin_amdgcn_mfma_f32_16x16x32_bf16(A00, B.a0, acc0, 0, 0, 0);
  acc0 = __builtin_amdgcn_mfma_f32_16x16x32_bf16(A01, B.a0, acc0, 0, 0, 0);
  acc0 = __builtin_amdgcn_mfma_f32_16x16x32_bf16(A02, B.a0, acc0, 0, 0, 0);
  acc0 = __builtin_amdgcn_mfma_f32_16x16x32_bf16(A00, B.a1, acc0, 0, 0, 0);
  acc0 = __builtin_amdgcn_mfma_f32_16x16x32_bf16(A01, B.a1, acc0, 0, 0, 0);
  acc0 = __builtin_amdgcn_mfma_f32_16x16x32_bf16(A00, B.a2, acc0, 0, 0, 0);
  acc1 = __builtin_amdgcn_mfma_f32_16x16x32_bf16(A10, B.a0, acc1, 0, 0, 0);
  acc1 = __builtin_amdgcn_mfma_f32_16x16x32_bf16(A11, B.a0, acc1, 0, 0, 0);
  acc1 = __builtin_amdgcn_mfma_f32_16x16x32_bf16(A12, B.a0, acc1, 0, 0, 0);
  acc1 = __builtin_amdgcn_mfma_f32_16x16x32_bf16(A10, B.a1, acc1, 0, 0, 0);
  acc1 = __builtin_amdgcn_mfma_f32_16x16x32_bf16(A11, B.a1, acc1, 0, 0, 0);
  acc1 = __builtin_amdgcn_mfma_f32_16x16x32_bf16(A10, B.a2, acc1, 0, 0, 0);
}

// ---------------------------------------------------------------------------
// Fused edge+dense kernel. Wt0/1/2 staged in LDS per block (padded stride):
// the compiler's low-VGPR rematerialization then re-reads LDS (~12 cyc)
// instead of L2 (~200-300 cyc) per fragment.
// ---------------------------------------------------------------------------
#define DENSE_BLOCKS 520

__global__ __launch_bounds__(256, 2) void fused_mfma_kernel(
    const float* __restrict__ x, const int* __restrict__ eidx,
    const float* __restrict__ pre, const short* __restrict__ Wt0,
    const short* __restrict__ Wt1, const short* __restrict__ Wt2,
    const float* __restrict__ W2, const float* __restrict__ b2,
    float* __restrict__ out, float* __restrict__ outP) {
  __shared__ short sWt0[32 * WSTRIDE];
  __shared__ short sWt1[32 * WSTRIDE];
  __shared__ short sWt2[32 * WSTRIDE];
  __shared__ float mir[4][256];

  // ---- stage Wt into LDS (vectorized, one-time) ----
  for (int idx = threadIdx.x; idx < 512; idx += 256) {
    const int h = idx >> 4;
    const int kk = (idx & 15) * 8;
    *(short8*)(sWt0 + h * WSTRIDE + kk) = *(const short8*)(Wt0 + h * 128 + kk);
    *(short8*)(sWt1 + h * WSTRIDE + kk) = *(const short8*)(Wt1 + h * 128 + kk);
    *(short8*)(sWt2 + h * WSTRIDE + kk) = *(const short8*)(Wt2 + h * 128 + kk);
  }
  __syncthreads();

  const int lane = threadIdx.x & 63;
  const int w = threadIdx.x >> 6;
  const int q = lane >> 4;
  const int c = lane & 15;

  if (blockIdx.x < DENSE_BLOCKS) {
    // ---------------- dense path: symmetric bilinear, triangular tiling ----
    const int T = blockIdx.x * 4 + w;
    int a = (int)((sqrtf(8.0f * (float)T + 1.0f) - 1.0f) * 0.5f);
    while ((a + 1) * (a + 2) / 2 <= T) ++a;
    while (a * (a + 1) / 2 > T) --a;
    const int b = T - a * (a + 1) / 2;
    const int j0 = a * 16;
    const int i0 = b * 16;
    const bool offdiag = (a != b);

    const float* xj = x + (size_t)(j0 + c) * FD;
    float jA[8], jB[8];
#pragma unroll
    for (int t = 0; t < 4; ++t) {
      jA[t] = xj[q * 8 + t];      jA[4 + t] = xj[q * 8 + 4 + t];
      jB[t] = xj[32 + q * 8 + t]; jB[4 + t] = xj[32 + q * 8 + 4 + t];
    }

    const floatx4 psA_j = *(const floatx4*)(pre + (j0 + c) * HD + q * 4);
    const floatx4 psB_j = *(const floatx4*)(pre + (j0 + c) * HD + 16 + q * 4);
    const floatx4 pdA_j = *(const floatx4*)(pre + NN * HD + (j0 + c) * HD + q * 4);
    const floatx4 pdB_j = *(const floatx4*)(pre + NN * HD + (j0 + c) * HD + 16 + q * 4);
    const floatx4 w2A = *(const floatx4*)(W2 + q * 4);
    const floatx4 w2B = *(const floatx4*)(W2 + 16 + q * 4);
    const float b2v = b2[0];

    for (int ii = 0; ii < 16; ++ii) {
      const int i = i0 + ii;
      const float* xi = x + (size_t)i * FD;
      const floatx4 psA_i = *(const floatx4*)(pre + i * HD + q * 4);
      const floatx4 psB_i = *(const floatx4*)(pre + i * HD + 16 + q * 4);
      floatx4 acc0 = {0.0f, 0.0f, 0.0f, 0.0f};
      floatx4 acc1 = {0.0f, 0.0f, 0.0f, 0.0f};

      {
        const floatx4 i0v = *(const floatx4*)(xi + q * 8);
        const floatx4 i1v = *(const floatx4*)(xi + q * 8 + 4);
        float ad[8], pr[8];
#pragma unroll
        for (int t = 0; t < 4; ++t) {
          ad[t] = fabsf(i0v[t] - jA[t]);         pr[t] = i0v[t] * jA[t];
          ad[4 + t] = fabsf(i1v[t] - jA[4 + t]); pr[4 + t] = i1v[t] * jA[4 + t];
        }
        const short8 fad = pack8(ad);
        const short8 fpr = pack8(pr);
        const short8 A00 = *(const short8*)(sWt0 + c * WSTRIDE + q * 8);
        const short8 A10 = *(const short8*)(sWt0 + (16 + c) * WSTRIDE + q * 8);
        const short8 A02 = *(const short8*)(sWt0 + c * WSTRIDE + 64 + q * 8);
        const short8 A12 = *(const short8*)(sWt0 + (16 + c) * WSTRIDE + 64 + q * 8);
        acc0 = __builtin_amdgcn_mfma_f32_16x16x32_bf16(A00, fad, acc0, 0, 0, 0);
        acc1 = __builtin_amdgcn_mfma_f32_16x16x32_bf16(A10, fad, acc1, 0, 0, 0);
        acc0 = __builtin_amdgcn_mfma_f32_16x16x32_bf16(A02, fpr, acc0, 0, 0, 0);
        acc1 = __builtin_amdgcn_mfma_f32_16x16x32_bf16(A12, fpr, acc1, 0, 0, 0);
      }
      {
        const floatx4 i0v = *(const floatx4*)(xi + 32 + q * 8);
        const floatx4 i1v = *(const floatx4*)(xi + 32 + q * 8 + 4);
        float ad[8], pr[8];
#pragma unroll
        for (int t = 0; t < 4; ++t) {
          ad[t] = fabsf(i0v[t] - jB[t]);         pr[t] = i0v[t] * jB[t];
          ad[4 + t] = fabsf(i1v[t] - jB[4 + t]); pr[4 + t] = i1v[t] * jB[4 + t];
        }
        const short8 fad = pack8(ad);
        const short8 fpr = pack8(pr);
        const short8 A01 = *(const short8*)(sWt0 + c * WSTRIDE + 32 + q * 8);
        const short8 A11 = *(const short8*)(sWt0 + (16 + c) * WSTRIDE + 32 + q * 8);
        const short8 A03 = *(const short8*)(sWt0 + c * WSTRIDE + 96 + q * 8);
        const short8 A13 = *(const short8*)(sWt0 + (16 + c) * WSTRIDE + 96 + q * 8);
        acc0 = __builtin_amdgcn_mfma_f32_16x16x32_bf16(A01, fad, acc0, 0, 0, 0);
        acc1 = __builtin_amdgcn_mfma_f32_16x16x32_bf16(A11, fad, acc1, 0, 0, 0);
        acc0 = __builtin_amdgcn_mfma_f32_16x16x32_bf16(A03, fpr, acc0, 0, 0, 0);
        acc1 = __builtin_amdgcn_mfma_f32_16x16x32_bf16(A13, fpr, acc1, 0, 0, 0);
      }

      // forward: P[i][j0+c]
      float tv = 0.0f;
#pragma unroll
      for (int r = 0; r < 4; ++r) {
        tv = fmaf(fmaxf(acc0[r] + psA_i[r] + pdA_j[r], 0.0f), w2A[r], tv);
        tv = fmaf(fmaxf(acc1[r] + psB_i[r] + pdB_j[r], 0.0f), w2B[r], tv);
      }
      tv += __shfl_xor(tv, 16);
      tv += __shfl_xor(tv, 32);
      if (lane < 16) {
        outP[(size_t)i * NN + j0 + lane] = sigmoid_fast(tv + b2v);
      }

      if (offdiag) {
        const floatx4 pdA_i = *(const floatx4*)(pre + NN * HD + i * HD + q * 4);
        const floatx4 pdB_i = *(const floatx4*)(pre + NN * HD + i * HD + 16 + q * 4);
        float tm = 0.0f;
#pragma unroll
        for (int r = 0; r < 4; ++r) {
          tm = fmaf(fmaxf(acc0[r] + psA_j[r] + pdA_i[r], 0.0f), w2A[r], tm);
          tm = fmaf(fmaxf(acc1[r] + psB_j[r] + pdB_i[r], 0.0f), w2B[r], tm);
        }
        tm += __shfl_xor(tm, 16);
        tm += __shfl_xor(tm, 32);
        if (lane < 16) {
          mir[w][ii * 16 + lane] = sigmoid_fast(tm + b2v);
        }
      }
    }

    if (offdiag) {
      // coalesced mirror store: 16 rows x 64B contiguous segments
      const int r = lane >> 2;
      const int g = lane & 3;
      floatx4 v;
#pragma unroll
      for (int t = 0; t < 4; ++t) v[t] = mir[w][(4 * g + t) * 16 + r];
      *(floatx4*)(outP + (size_t)(j0 + r) * NN + i0 + 4 * g) = v;
    }
  } else {
    // ---------------- edge path: split-MFMA, fp32-accurate ----------------
    const int e0 = ((blockIdx.x - DENSE_BLOCKS) * 4 + w) * 16;

    const bool is64 = (eidx[1] == 0) && (eidx[3] == 0) && (eidx[5] == 0);
    int s_c, d_c;
    if (is64) {
      s_c = eidx[2 * (e0 + c)];
      d_c = eidx[2 * (EE + e0 + c)];
    } else {
      s_c = eidx[e0 + c];
      d_c = eidx[EE + e0 + c];
    }
    const float* xs = x + (size_t)s_c * FD;
    const float* xd = x + (size_t)d_c * FD;

    floatx4 acc0, acc1;
    {
      const floatx4 psA = *(const floatx4*)(pre + s_c * HD + q * 4);
      const floatx4 psB = *(const floatx4*)(pre + s_c * HD + 16 + q * 4);
      const floatx4 pdA = *(const floatx4*)(pre + NN * HD + d_c * HD + q * 4);
      const floatx4 pdB = *(const floatx4*)(pre + NN * HD + d_c * HD + 16 + q * 4);
#pragma unroll
      for (int r = 0; r < 4; ++r) {
        acc0[r] = psA[r] + pdA[r];
        acc1[r] = psB[r] + pdB[r];
      }
    }

    {
      const floatx4 s0 = *(const floatx4*)(xs + q * 8);
      const floatx4 s1 = *(const floatx4*)(xs + q * 8 + 4);
      const floatx4 d0 = *(const floatx4*)(xd + q * 8);
      const floatx4 d1 = *(const floatx4*)(xd + q * 8 + 4);
      float ad[8], pr[8];
#pragma unroll
      for (int t = 0; t < 4; ++t) {
        ad[t] = fabsf(s0[t] - d0[t]);     pr[t] = s0[t] * d0[t];
        ad[4 + t] = fabsf(s1[t] - d1[t]); pr[4 + t] = s1[t] * d1[t];
      }
      edge_chunk(ad, sWt0, sWt1, sWt2, c, q, 0, acc0, acc1);
      edge_chunk(pr, sWt0, sWt1, sWt2, c, q, 2, acc0, acc1);
    }
    {
      const floatx4 s0 = *(const floatx4*)(xs + 32 + q * 8);
      const floatx4 s1 = *(const floatx4*)(xs + 32 + q * 8 + 4);
      const floatx4 d0 = *(const floatx4*)(xd + 32 + q * 8);
      const floatx4 d1 = *(const floatx4*)(xd + 32 + q * 8 + 4);
      float ad[8], pr[8];
#pragma unroll
      for (int t = 0; t < 4; ++t) {
        ad[t] = fabsf(s0[t] - d0[t]);     pr[t] = s0[t] * d0[t];
        ad[4 + t] = fabsf(s1[t] - d1[t]); pr[4 + t] = s1[t] * d1[t];
      }
      edge_chunk(ad, sWt0, sWt1, sWt2, c, q, 1, acc0, acc1);
      edge_chunk(pr, sWt0, sWt1, sWt2, c, q, 3, acc0, acc1);
    }

    const floatx4 w2A = *(const floatx4*)(W2 + q * 4);
    const floatx4 w2B = *(const floatx4*)(W2 + 16 + q * 4);
    float tv = 0.0f;
#pragma unroll
    for (int r = 0; r < 4; ++r) {
      tv = fmaf(fmaxf(acc0[r], 0.0f), w2A[r], tv);
      tv = fmaf(fmaxf(acc1[r], 0.0f), w2B[r], tv);
    }
    tv += __shfl_xor(tv, 16);
    tv += __shfl_xor(tv, 32);
    if (lane < 16) {
      const int e = e0 + lane;
      const float z = tv + b2[0];
      out[e] = sigmoid_f(z);
      out[EE + e] = (z > -0.40546510810816444f) ? 1.0f : 0.0f;
    }
  }
}

// ---------------------------------------------------------------------------
// Fallbacks (no-workspace path)
// ---------------------------------------------------------------------------
__device__ __forceinline__ float pair_logit_full(
    const float* __restrict__ xs, const float* __restrict__ xd,
    const float* __restrict__ W1, const float* __restrict__ b1,
    const float* __restrict__ W2, const float b2v) {
  float acc[HD];
#pragma unroll
  for (int h = 0; h < HD; ++h) acc[h] = b1[h];
#pragma unroll 1
  for (int f = 0; f < FD; ++f) {
    const float a = xs[f], b = xd[f];
    const float ad = fabsf(a - b), pr = a * b;
#pragma unroll
    for (int h = 0; h < HD; ++h) {
      float t0 = fmaf(a, W1[f * HD + h], acc[h]);
      t0 = fmaf(b, W1[(FD + f) * HD + h], t0);
      t0 = fmaf(ad, W1[(2 * FD + f) * HD + h], t0);
      acc[h] = fmaf(pr, W1[(3 * FD + f) * HD + h], t0);
    }
  }
  float z = b2v;
#pragma unroll
  for (int h = 0; h < HD; ++h) z = fmaf(fmaxf(acc[h], 0.0f), W2[h], z);
  return z;
}

__global__ __launch_bounds__(256) void edge_kernel_fb(
    const float* __restrict__ x, const int* __restrict__ eidx,
    const float* __restrict__ W1, const float* __restrict__ b1,
    const float* __restrict__ W2, const float* __restrict__ b2,
    float* __restrict__ out) {
  const int e = blockIdx.x * 256 + threadIdx.x;
  const bool is64 = (eidx[1] == 0) && (eidx[3] == 0) && (eidx[5] == 0);
  int s, d;
  if (is64) { s = eidx[2 * e]; d = eidx[2 * (EE + e)]; }
  else { s = eidx[e]; d = eidx[EE + e]; }
  const float z = pair_logit_full(x + (size_t)s * FD, x + (size_t)d * FD,
                                  W1, b1, W2, b2[0]);
  const float p = sigmoid_f(z);
  out[e] = p;
  out[EE + e] = (p > 0.4f) ? 1.0f : 0.0f;
}

__global__ __launch_bounds__(256) void dense_full_fb(
    const float* __restrict__ x, const float* __restrict__ W1,
    const float* __restrict__ b1, const float* __restrict__ W2,
    const float* __restrict__ b2, float* __restrict__ outP) {
  const int j = blockIdx.x * 64 + threadIdx.x % 64;
  const int i = blockIdx.y * 4 + threadIdx.x / 64;
  const float z = pair_logit_full(x + (size_t)i * FD, x + (size_t)j * FD,
                                  W1, b1, W2, b2[0]);
  outP[(size_t)i * NN + j] = sigmoid_f(z);
}

extern "C" void kernel_launch(void* const* d_in, const int* in_sizes, int n_in,
                              void* d_out, int out_size, void* d_ws, size_t ws_size,
                              hipStream_t stream) {
  const float* x  = (const float*)d_in[0];
  const int*  ei  = (const int*)d_in[1];
  const float* W1 = (const float*)d_in[3];
  const float* b1 = (const float*)d_in[4];
  const float* W2 = (const float*)d_in[5];
  const float* b2 = (const float*)d_in[6];
  float* out  = (float*)d_out;   // [0,EE) probs, [EE,2EE) actions
  float* outP = out + 2 * EE;    // [2EE, 2EE+NN*NN) P

  const size_t pre_bytes = (size_t)2 * NN * HD * sizeof(float);
  const size_t wt_elems = 32 * 128;
  const size_t need = pre_bytes + 3 * wt_elems * sizeof(short);
  if (ws_size >= need) {
    float* pre = (float*)d_ws;
    short* Wt0 = (short*)((char*)d_ws + pre_bytes);
    short* Wt1 = Wt0 + wt_elems;
    short* Wt2 = Wt1 + wt_elems;
    pre_kernel3<<<257, 256, 0, stream>>>(x, W1, b1, pre, Wt0, Wt1, Wt2);
    fused_mfma_kernel<<<DENSE_BLOCKS + 1024, 256, 0, stream>>>(
        x, ei, pre, Wt0, Wt1, Wt2, W2, b2, out, outP);
  } else {
    edge_kernel_fb<<<EE / 256, 256, 0, stream>>>(x, ei, W1, b1, W2, b2, out);
    dense_full_fb<<<dim3(NN / 64, NN / 4), 256, 0, stream>>>(
        x, W1, b1, W2, b2, outP);
  }
}